// Round 4
// baseline (420.313 us; speedup 1.0000x reference)
//
#include <hip/hip_runtime.h>
#include <hip/hip_bf16.h>
#include <math.h>

#define NBINS 18
#define NB 2
#define NC 16
#define FP 30
#define FA 50
#define NS 20
#define NT 1024
#define TS 128              // t per staging chunk
#define NCH (NT / TS)       // 8
#define PGSZ 15             // p's per block
#define NTHR 384

// ---------------- shared helpers ----------------
typedef __attribute__((ext_vector_type(8))) short bf16x8;
typedef __attribute__((ext_vector_type(4))) float f32x4;

__device__ inline float u2f(unsigned int u) { return __builtin_bit_cast(float, u); }
__device__ inline unsigned short f2bf(float x) {
    unsigned int u = __builtin_bit_cast(unsigned int, x);
    unsigned int r = (u + 0x7FFFu + ((u >> 16) & 1u)) >> 16;   // RNE
    return (unsigned short)r;
}
// HW RNE float->bf16 (bit-identical to f2bf)
__device__ inline unsigned short bfr(float x) {
    return __builtin_bit_cast(unsigned short, __float2bfloat16(x));
}

// Exact bucketize: b = #{j in 1..17 : cuts[j] < v}; arithmetic estimate +/-1,
// fixup against LDS cutoff table makes it bit-exact vs the compare-count.
__device__ __forceinline__ int bin_of(float v, const float* cl) {
    int b0 = __float2int_rd(fmaf(v, 2.86478897565f, 9.0f));   // (v+pi)*18/(2pi)
    b0 = b0 < 0 ? 0 : (b0 > 17 ? 17 : b0);
    const float lo = cl[b0];
    const float hi = cl[b0 + 1];
    return b0 + (int)((b0 < 17) & (hi < v)) - (int)((b0 > 0) & !(lo < v));
}

// async 16B global -> LDS (wave-uniform LDS base + lane*16; global addr per-lane)
__device__ __forceinline__ void gl_lds16(const void* g, void* l) {
    __builtin_amdgcn_global_load_lds(
        (const __attribute__((address_space(1))) unsigned int*)g,
        (__attribute__((address_space(3))) unsigned int*)l, 16, 0, 0);
}

// ======================================================================
// Kernel A: one-pass conversion.
//   amp  -> bf16 hi/lo planes, layout [bcs][ch][a][pl][c] (uint4 units,
//           row = 32 u4: pl0 c0..15, pl1 c0..15; chunk c holds t=8c..8c+7)
//   pha  -> packed bin bytes, layout [((bc*30+p)*20+s)*8+ch][tc] (uint units)
// ======================================================================
#define NAMP4 8192000           // amp float4 count
#define NPHA4 4915200           // pha float4 count

__global__ __launch_bounds__(256) void mi_convert(const float* __restrict__ pha,
                                                  const float* __restrict__ amp,
                                                  const float* __restrict__ cut,
                                                  uint2* __restrict__ wsAmp,
                                                  unsigned* __restrict__ wsBin) {
    __shared__ float cl[19];
    if (threadIdx.x < 19) cl[threadIdx.x] = cut[threadIdx.x];
    __syncthreads();
    const int stride = gridDim.x * 256;
    for (int idx = blockIdx.x * 256 + threadIdx.x; idx < NAMP4 + NPHA4; idx += stride) {
        if (idx < NAMP4) {
            const float4 v4 = *((const float4*)amp + idx);
            const int t  = (idx & 255) << 2;
            const int r  = idx >> 8;            // (bc*50+a)*20+s
            const int s  = r % 20;
            const int q  = r / 20;
            const int a  = q % 50;
            const int bc = q / 50;
            const int ch = t >> 7, tc = t & 127;
            const unsigned short h0 = bfr(v4.x), h1 = bfr(v4.y);
            const unsigned short h2 = bfr(v4.z), h3 = bfr(v4.w);
            const unsigned short q0 = bfr(v4.x - u2f((unsigned)h0 << 16));
            const unsigned short q1 = bfr(v4.y - u2f((unsigned)h1 << 16));
            const unsigned short q2 = bfr(v4.z - u2f((unsigned)h2 << 16));
            const unsigned short q3 = bfr(v4.w - u2f((unsigned)h3 << 16));
            uint2 hv, lv;
            hv.x = (unsigned)h0 | ((unsigned)h1 << 16); hv.y = (unsigned)h2 | ((unsigned)h3 << 16);
            lv.x = (unsigned)q0 | ((unsigned)q1 << 16); lv.y = (unsigned)q2 | ((unsigned)q3 << 16);
            const size_t tile_u2 = (size_t)((bc * 20 + s) * NCH + ch) * 3200;
            const int c4 = tc >> 3, half = (tc >> 2) & 1;
            wsAmp[tile_u2 + (size_t)(a * 32 + c4) * 2 + half] = hv;        // pl=0 (hi)
            wsAmp[tile_u2 + (size_t)(a * 32 + 16 + c4) * 2 + half] = lv;   // pl=1 (lo)
        } else {
            const int j = idx - NAMP4;
            const float4 v4 = *((const float4*)pha + j);
            const int t  = (j & 255) << 2;
            const int r  = j >> 8;              // (bc*30+p)*20+s
            const int s  = r % 20;
            const int q  = r / 20;
            const int p  = q % 30;
            const int bc = q / 30;
            const int ch = t >> 7, tc = t & 127;
            const unsigned pk = (unsigned)bin_of(v4.x, cl)
                              | ((unsigned)bin_of(v4.y, cl) << 8)
                              | ((unsigned)bin_of(v4.z, cl) << 16)
                              | ((unsigned)bin_of(v4.w, cl) << 24);
            wsBin[(size_t)(((bc * FP + p) * NS + s) * NCH + ch) * 32 + (tc >> 2)] = pk;
        }
    }
}

// ======================================================================
// Kernel B: MFMA from preconverted data, global_load_lds double-buffered,
// one barrier per chunk. LDS per buffer: 64 a-rows x 512B + 2KB bins.
// Swizzle: LDS chunk c' holds t-chunk c'^(a&7) (per-lane global source).
// ======================================================================
#define ROWB 512                 // bytes per a-row ([pl][c] = 2*256)
#define AMPB (64 * ROWB)         // 32768
#define BINB2 2048
#define BUFB (AMPB + BINB2)      // 34816
#define SMEM3 (2 * BUFB)         // 69632
#define ACCW 52

template <bool DIRECT>
__global__ __launch_bounds__(NTHR) void mi_mfma_pre(const uint4* __restrict__ wsAmp,
                                                    const unsigned* __restrict__ wsBin,
                                                    float* __restrict__ outp) {
    __shared__ __align__(16) char smem[SMEM3];
    float* accs = (float*)smem;   // epilogue reuse (buf0)

    const int g   = blockIdx.x;
    const int pg  = (g >> 3) & 1;
    const int bcs = (g >> 4) * 8 + (g & 7);
    const int s   = bcs % NS;
    const int bc  = bcs / NS;
    const int p0  = pg * PGSZ;

    const int tid  = threadIdx.x;
    const int lane = tid & 63;
    const int w    = tid >> 6;            // 0..5
    const int l16  = lane & 15;
    const int quad = lane >> 4;
    const int x7   = l16 & 7;

    // per-lane one-hot row params
    int pm[3]; unsigned kx[3];
    #pragma unroll
    for (int mt = 0; mt < 3; ++mt) {
        const int row = w * 48 + mt * 16 + l16;
        const int valid = row < PGSZ * NBINS;
        const int p = valid ? (row / NBINS) : (PGSZ - 1);
        const int kb = valid ? (row - p * NBINS) : 31;
        pm[mt] = p;
        kx[mt] = (unsigned)kb * 0x01010101u;
    }

    // count row (a=50) in BOTH buffers: hi=1.0 bf16 (pl0), lo=0 (pl1)
    for (int t = tid; t < TS; t += NTHR) {
        #pragma unroll
        for (int b = 0; b < 2; ++b) {
            short* rowp = (short*)(smem + b * BUFB + 50 * ROWB);
            rowp[t] = (short)0x3F80;
            rowp[128 + t] = 0;
        }
    }

    f32x4 acc[3][4];
    #pragma unroll
    for (int mt = 0; mt < 3; ++mt)
        #pragma unroll
        for (int nt = 0; nt < 4; ++nt) acc[mt][nt] = (f32x4){0.f, 0.f, 0.f, 0.f};

    const uint4* ampT = wsAmp + (size_t)bcs * (NCH * 1600);
    const int binRow0 = (bc * FP + p0) * NS + s;

    // 27 gload_lds slots/chunk: 0..24 amp (rows 2j,2j+1), 25..26 bins.
    // Wave w issues slots {w+6k}; all branches wave-uniform.
    auto ISSUE = [&](int ch, int bsel) {
        char* buf = smem + bsel * BUFB;
        const uint4* at = ampT + ch * 1600;
        #pragma unroll
        for (int k = 0; k < 5; ++k) {
            const int slot = w + 6 * k;
            if (slot < 25) {
                const int a  = 2 * slot + (lane >> 5);
                const int pl = (lane >> 4) & 1;
                const int cs = (lane & 15) ^ (a & 7);   // pre-swizzled source chunk
                gl_lds16(at + a * 32 + pl * 16 + cs, buf + slot * 1024);
            } else if (slot < 27) {
                const int jb = slot - 25;
                int p_l = 8 * jb + (lane >> 3);
                if (p_l > 14) p_l = 14;                 // pad lanes re-read row 14
                const int c = lane & 7;
                gl_lds16(wsBin + ((size_t)(binRow0 + p_l * NS) * NCH + ch) * 32 + c * 4,
                         buf + AMPB + jb * 1024);
            }
        }
    };

    auto MFMA_PH = [&](int bsel) {
        const char* buf = smem + bsel * BUFB;
        #pragma unroll
        for (int ks = 0; ks < 4; ++ks) {
            bf16x8 af[3];
            #pragma unroll
            for (int mt = 0; mt < 3; ++mt) {
                const uint2 d = *(const uint2*)(buf + AMPB + pm[mt] * 128 + ks * 32 + quad * 8);
                const unsigned x0 = d.x ^ kx[mt];
                const unsigned x1 = d.y ^ kx[mt];
                const unsigned f0 = ~(x0 + 0x7F7F7F7Fu) & 0x80808080u;
                const unsigned f1 = ~(x1 + 0x7F7F7F7Fu) & 0x80808080u;
                uint4 a4;
                a4.x = (f0 & 0x80u) * 0x7Fu + ((f0 >> 8) & 0x80u) * 0x7F0000u;
                a4.y = ((f0 >> 16) & 0x80u) * 0x7Fu + (f0 >> 24) * 0x7F0000u;
                a4.z = (f1 & 0x80u) * 0x7Fu + ((f1 >> 8) & 0x80u) * 0x7F0000u;
                a4.w = ((f1 >> 16) & 0x80u) * 0x7Fu + (f1 >> 24) * 0x7F0000u;
                af[mt] = __builtin_bit_cast(bf16x8, a4);
            }
            const int cidx = (4 * ks + quad) ^ x7;      // swizzled read chunk
            bf16x8 bh[4], bl[4];
            #pragma unroll
            for (int nt = 0; nt < 4; ++nt) {
                const char* bp = buf + (nt * 16 + l16) * ROWB + cidx * 16;
                bh[nt] = *(const bf16x8*)bp;
                bl[nt] = *(const bf16x8*)(bp + 256);
            }
            #pragma unroll
            for (int mt = 0; mt < 3; ++mt)
                #pragma unroll
                for (int nt = 0; nt < 4; ++nt)
                    acc[mt][nt] = __builtin_amdgcn_mfma_f32_16x16x32_bf16(af[mt], bh[nt], acc[mt][nt], 0, 0, 0);
            #pragma unroll
            for (int mt = 0; mt < 3; ++mt)
                #pragma unroll
                for (int nt = 0; nt < 4; ++nt)
                    acc[mt][nt] = __builtin_amdgcn_mfma_f32_16x16x32_bf16(af[mt], bl[nt], acc[mt][nt], 0, 0, 0);
        }
    };

    // pipeline: barrier drains ISSUE(ch) (auto vmcnt0) after a full MFMA phase
    // of flight time; ISSUE(ch+1) then flies under MFMA(ch).
    ISSUE(0, 0);
    for (int ch = 0; ch < NCH; ++ch) {
        __syncthreads();
        if (ch + 1 < NCH) ISSUE(ch + 1, (ch + 1) & 1);
        MFMA_PH(ch & 1);
    }
    __syncthreads();   // last MFMA (buf1) done before smem (buf0) reuse

    // ---- epilogue: identical to proven r2 ----
    const float ln18 = 2.8903717578961645f;
    const float inv_ln18 = 0.34598234401512115f;
    #pragma unroll 1
    for (int ph = 0; ph < 3; ++ph) {
        const int rlo = ph * 90, rhi = rlo + 90;
        #pragma unroll
        for (int mt = 0; mt < 3; ++mt) {
            #pragma unroll
            for (int nt = 0; nt < 4; ++nt) {
                const int col = nt * 16 + l16;
                if (col <= FA) {
                    #pragma unroll
                    for (int r2 = 0; r2 < 4; ++r2) {
                        const int row = w * 48 + mt * 16 + quad * 4 + r2;
                        if (row >= rlo && row < rhi)
                            accs[(row - rlo) * ACCW + col] = acc[mt][nt][r2];
                    }
                }
            }
        }
        __syncthreads();
        if (tid < 5 * FA) {
            const int pidx = tid / FA;
            const int a = tid - pidx * FA;
            float means[NBINS];
            float tot = 0.f;
            #pragma unroll
            for (int k = 0; k < NBINS; ++k) {
                const float sum = accs[(pidx * NBINS + k) * ACCW + a];
                const float cnt = accs[(pidx * NBINS + k) * ACCW + FA];
                const float m = sum / (cnt + 1e-9f);
                means[k] = m;
                tot += m;
            }
            const float rden = 1.0f / (tot + 1e-9f);
            float ent = 0.f;
            #pragma unroll
            for (int k = 0; k < NBINS; ++k) {
                const float pr = means[k] * rden;
                ent += pr * logf(pr + 1e-9f);
            }
            const float mi = (ln18 + ent) * inv_ln18;
            const int p = ph * 5 + pidx;
            const int oi = (bc * FP + p0 + p) * FA + a;
            if (DIRECT) {
                atomicAdd(&outp[oi], mi * (1.0f / NS));
            } else {
                outp[(size_t)s * (NB * NC * FP * FA) + oi] = mi;
            }
        }
        __syncthreads();
    }
}

// ======================================================================
// Fallback: round-2 proven kernel (191 us), verbatim.
// ======================================================================
#define BSTR 136
#define BINSTR 136
#define BIN_OFF (2 * 64 * BSTR * 2)       // 34816
#define SMEM_B (BIN_OFF + PGSZ * BINSTR)  // 36856

template <bool DIRECT>
__global__ __launch_bounds__(NTHR) void mi_mfma(const float* __restrict__ pha,
                                                const float* __restrict__ amp,
                                                const float* __restrict__ cut,
                                                float* __restrict__ outp) {
    __shared__ __align__(16) char smem[SMEM_B];
    short* Bh = (short*)smem;
    float* accs = (float*)smem;

    const int g   = blockIdx.x;
    const int pg  = (g >> 3) & 1;
    const int bcs = (g >> 4) * 8 + (g & 7);
    const int s   = bcs % NS;
    const int bc  = bcs / NS;
    const int p0  = pg * PGSZ;

    const int tid  = threadIdx.x;
    const int lane = tid & 63;
    const int w    = tid >> 6;
    const int l16  = lane & 15;
    const int quad = lane >> 4;

    float cuts[NBINS];
    #pragma unroll
    for (int j = 1; j <= 17; ++j) cuts[j] = cut[j];

    int pm[3]; unsigned kx[3];
    #pragma unroll
    for (int mt = 0; mt < 3; ++mt) {
        const int row = w * 48 + mt * 16 + l16;
        const int valid = row < PGSZ * NBINS;
        const int p = valid ? (row / NBINS) : (PGSZ - 1);
        const int kb = valid ? (row - p * NBINS) : 31;
        pm[mt] = p;
        kx[mt] = (unsigned)kb * 0x01010101u;
    }

    for (int t = tid; t < TS; t += NTHR) {
        Bh[FA * BSTR + t] = (short)0x3F80;
        Bh[64 * BSTR + FA * BSTR + t] = 0;
    }

    f32x4 acc[3][4];
    #pragma unroll
    for (int mt = 0; mt < 3; ++mt)
        #pragma unroll
        for (int nt = 0; nt < 4; ++nt) acc[mt][nt] = (f32x4){0.f, 0.f, 0.f, 0.f};

    const size_t phabase0 = ((size_t)(bc * FP + p0) * NS + s) * NT;
    const size_t ampbase0 = ((size_t)bc * FA * NS + s) * NT;

    float4 ph_pf[2];
    float4 am_pf[5];

    auto LOAD = [&](int ch) {
        const float* pb = pha + phabase0 + ch * TS;
        #pragma unroll
        for (int r = 0; r < 2; ++r) {
            const int i = tid + r * NTHR;
            if (i < PGSZ * (TS / 4)) {
                const int p = i >> 5, tq = i & 31;
                ph_pf[r] = *(const float4*)(pb + (size_t)p * (NS * NT) + tq * 4);
            }
        }
        const float* ab = amp + ampbase0 + ch * TS;
        #pragma unroll
        for (int r = 0; r < 5; ++r) {
            const int i = tid + r * NTHR;
            if (i < FA * (TS / 4)) {
                const int a_ = i >> 5, tq = i & 31;
                am_pf[r] = *(const float4*)(ab + (size_t)a_ * (NS * NT) + tq * 4);
            }
        }
    };

    LOAD(0);

    for (int ch = 0; ch < NCH; ++ch) {
        __syncthreads();
        #pragma unroll
        for (int r = 0; r < 2; ++r) {
            const int i = tid + r * NTHR;
            if (i < PGSZ * (TS / 4)) {
                const int p = i >> 5, tq = i & 31;
                const float4 v4 = ph_pf[r];
                int b0 = 0, b1 = 0, b2 = 0, b3 = 0;
                #pragma unroll
                for (int j = 1; j <= 17; ++j) {
                    b0 += (cuts[j] < v4.x) ? 1 : 0;
                    b1 += (cuts[j] < v4.y) ? 1 : 0;
                    b2 += (cuts[j] < v4.z) ? 1 : 0;
                    b3 += (cuts[j] < v4.w) ? 1 : 0;
                }
                const unsigned pk = (unsigned)b0 | ((unsigned)b1 << 8)
                                  | ((unsigned)b2 << 16) | ((unsigned)b3 << 24);
                *(unsigned*)(smem + BIN_OFF + p * BINSTR + tq * 4) = pk;
            }
        }
        #pragma unroll
        for (int r = 0; r < 5; ++r) {
            const int i = tid + r * NTHR;
            if (i < FA * (TS / 4)) {
                const int a_ = i >> 5, tq = i & 31;
                const float4 v4 = am_pf[r];
                const unsigned short h0 = f2bf(v4.x), h1 = f2bf(v4.y);
                const unsigned short h2 = f2bf(v4.z), h3 = f2bf(v4.w);
                const unsigned short q0 = f2bf(v4.x - u2f((unsigned)h0 << 16));
                const unsigned short q1 = f2bf(v4.y - u2f((unsigned)h1 << 16));
                const unsigned short q2 = f2bf(v4.z - u2f((unsigned)h2 << 16));
                const unsigned short q3 = f2bf(v4.w - u2f((unsigned)h3 << 16));
                short* dst = Bh + a_ * BSTR + tq * 4;
                uint2 hv; hv.x = (unsigned)h0 | ((unsigned)h1 << 16); hv.y = (unsigned)h2 | ((unsigned)h3 << 16);
                uint2 lv; lv.x = (unsigned)q0 | ((unsigned)q1 << 16); lv.y = (unsigned)q2 | ((unsigned)q3 << 16);
                *(uint2*)dst = hv;
                *(uint2*)(dst + 64 * BSTR) = lv;
            }
        }
        __syncthreads();
        if (ch + 1 < NCH) LOAD(ch + 1);
        #pragma unroll
        for (int ks = 0; ks < 4; ++ks) {
            bf16x8 af[3];
            #pragma unroll
            for (int mt = 0; mt < 3; ++mt) {
                const uint2 d = *(const uint2*)(smem + BIN_OFF + pm[mt] * BINSTR + ks * 32 + quad * 8);
                const unsigned x0 = d.x ^ kx[mt];
                const unsigned x1 = d.y ^ kx[mt];
                const unsigned f0 = ~(x0 + 0x7F7F7F7Fu) & 0x80808080u;
                const unsigned f1 = ~(x1 + 0x7F7F7F7Fu) & 0x80808080u;
                uint4 a4;
                a4.x = (f0 & 0x80u) * 0x7Fu + ((f0 >> 8) & 0x80u) * 0x7F0000u;
                a4.y = ((f0 >> 16) & 0x80u) * 0x7Fu + (f0 >> 24) * 0x7F0000u;
                a4.z = (f1 & 0x80u) * 0x7Fu + ((f1 >> 8) & 0x80u) * 0x7F0000u;
                a4.w = ((f1 >> 16) & 0x80u) * 0x7Fu + (f1 >> 24) * 0x7F0000u;
                af[mt] = __builtin_bit_cast(bf16x8, a4);
            }
            bf16x8 bh[4], bl[4];
            #pragma unroll
            for (int nt = 0; nt < 4; ++nt) {
                const short* bp = Bh + (nt * 16 + l16) * BSTR + ks * 32 + quad * 8;
                bh[nt] = *(const bf16x8*)bp;
                bl[nt] = *(const bf16x8*)(bp + 64 * BSTR);
            }
            #pragma unroll
            for (int mt = 0; mt < 3; ++mt)
                #pragma unroll
                for (int nt = 0; nt < 4; ++nt)
                    acc[mt][nt] = __builtin_amdgcn_mfma_f32_16x16x32_bf16(af[mt], bh[nt], acc[mt][nt], 0, 0, 0);
            #pragma unroll
            for (int mt = 0; mt < 3; ++mt)
                #pragma unroll
                for (int nt = 0; nt < 4; ++nt)
                    acc[mt][nt] = __builtin_amdgcn_mfma_f32_16x16x32_bf16(af[mt], bl[nt], acc[mt][nt], 0, 0, 0);
        }
    }
    __syncthreads();

    const float ln18 = 2.8903717578961645f;
    const float inv_ln18 = 0.34598234401512115f;
    #pragma unroll 1
    for (int ph = 0; ph < 3; ++ph) {
        const int rlo = ph * 90, rhi = rlo + 90;
        #pragma unroll
        for (int mt = 0; mt < 3; ++mt) {
            #pragma unroll
            for (int nt = 0; nt < 4; ++nt) {
                const int col = nt * 16 + l16;
                if (col <= FA) {
                    #pragma unroll
                    for (int r2 = 0; r2 < 4; ++r2) {
                        const int row = w * 48 + mt * 16 + quad * 4 + r2;
                        if (row >= rlo && row < rhi)
                            accs[(row - rlo) * ACCW + col] = acc[mt][nt][r2];
                    }
                }
            }
        }
        __syncthreads();
        if (tid < 5 * FA) {
            const int pidx = tid / FA;
            const int a = tid - pidx * FA;
            float means[NBINS];
            float tot = 0.f;
            #pragma unroll
            for (int k = 0; k < NBINS; ++k) {
                const float sum = accs[(pidx * NBINS + k) * ACCW + a];
                const float cnt = accs[(pidx * NBINS + k) * ACCW + FA];
                const float m = sum / (cnt + 1e-9f);
                means[k] = m;
                tot += m;
            }
            const float rden = 1.0f / (tot + 1e-9f);
            float ent = 0.f;
            #pragma unroll
            for (int k = 0; k < NBINS; ++k) {
                const float pr = means[k] * rden;
                ent += pr * logf(pr + 1e-9f);
            }
            const float mi = (ln18 + ent) * inv_ln18;
            const int p = ph * 5 + pidx;
            const int oi = (bc * FP + p0 + p) * FA + a;
            if (DIRECT) {
                atomicAdd(&outp[oi], mi * (1.0f / NS));
            } else {
                outp[(size_t)s * (NB * NC * FP * FA) + oi] = mi;
            }
        }
        __syncthreads();
    }
}

__global__ void mi_reduce(const float* __restrict__ partial, float* __restrict__ out) {
    const int i = blockIdx.x * 256 + threadIdx.x;
    const int n = NB * NC * FP * FA;
    if (i < n) {
        float acc = 0.f;
        #pragma unroll
        for (int j = 0; j < NS; ++j) acc += partial[(size_t)j * n + i];
        out[i] = acc * (1.0f / NS);
    }
}

extern "C" void kernel_launch(void* const* d_in, const int* in_sizes, int n_in,
                              void* d_out, int out_size, void* d_ws, size_t ws_size,
                              hipStream_t stream) {
    const float* pha = (const float*)d_in[0];
    const float* amp = (const float*)d_in[1];
    const float* cut = (const float*)d_in[2];
    float* out = (float*)d_out;

    const int nout = NB * NC * FP * FA;                      // 48000
    const size_t needP = (size_t)nout * NS * sizeof(float);  // 3,840,000
    const size_t WSAMP = (size_t)NAMP4 * 16;                 // 131,072,000
    const size_t WSBIN = (size_t)NPHA4 * 4;                  // 19,660,800
    const size_t need2 = needP + WSAMP + WSBIN;              // 154,572,800
    const dim3 grid(NB * NC * NS * 2);                       // 1280

    if (ws_size >= need2) {
        float* partial = (float*)d_ws;
        uint2* wsAmp = (uint2*)((char*)d_ws + needP);
        unsigned* wsBin = (unsigned*)((char*)d_ws + needP + WSAMP);
        mi_convert<<<2048, 256, 0, stream>>>(pha, amp, cut, wsAmp, wsBin);
        mi_mfma_pre<false><<<grid, NTHR, 0, stream>>>((const uint4*)wsAmp, wsBin, partial);
        mi_reduce<<<(nout + 255) / 256, 256, 0, stream>>>(partial, out);
    } else if (ws_size >= needP) {
        float* partial = (float*)d_ws;
        mi_mfma<false><<<grid, NTHR, 0, stream>>>(pha, amp, cut, partial);
        mi_reduce<<<(nout + 255) / 256, 256, 0, stream>>>(partial, out);
    } else {
        hipMemsetAsync(d_out, 0, (size_t)nout * sizeof(float), stream);
        mi_mfma<true><<<grid, NTHR, 0, stream>>>(pha, amp, cut, out);
    }
}